// Round 11
// baseline (92.769 us; speedup 1.0000x reference)
//
#include <hip/hip_runtime.h>
#include <math.h>

#define N_ANCH 87296
#define NCLS 91
#define NBINS 4096
#define K_CAND 256
#define CAP 512
#define MAX_OUT 100
#define IOU_TH 0.6f
#define NB 682
#define BT 128

// ws layout (bytes):
//      0: hist  (NBINS*4 = 16384)   zeroed by the graph's memset node
//  16384: cnt   (4)
//  16388: doneA (4)
//  16392: doneC (4)
//  16396: flag  (4)                 value = FB | 0x10000 when ready
//  16400: payload (CAP * 32 B)      4 x u64 per candidate, atomic-store only
#define WS_HDR 16400

__device__ __forceinline__ float sigmoidf_(float x) {
    return 1.0f / (1.0f + expf(-x));
}

__device__ __forceinline__ unsigned long long pack2f(float a, float b) {
    union { float f[2]; unsigned long long u; } t;
    t.f[0] = a; t.f[1] = b; return t.u;
}
__device__ __forceinline__ void unpack2f(unsigned long long u, float& a, float& b) {
    union { float f[2]; unsigned long long u; } t;
    t.u = u; a = t.f[0]; b = t.f[1];
}

// Verified suffix-scan threshold find over a 4096-bin LDS hist (r7-r10).
__device__ __forceinline__ void scan_thresh(const unsigned* hist, int lane,
                                            unsigned K, int* s_dst) {
    const uint4* h4 = (const uint4*)hist;       // 1024 uint4
    uint4 c[16];
    #pragma unroll
    for (int q = 0; q < 16; ++q) c[q] = h4[lane * 16 + q];

    unsigned local = 0;
    #pragma unroll
    for (int q = 0; q < 16; ++q) local += c[q].x + c[q].y + c[q].z + c[q].w;

    unsigned p = local;                          // suffix-inclusive scan
    #pragma unroll
    for (int d = 1; d < 64; d <<= 1) {
        unsigned t = (unsigned)__shfl_down((int)p, d, 64);
        if (lane + d < 64) p += t;
    }
    unsigned long long mask = __ballot(p >= K);
    int L = 63 - __clzll(mask);
    unsigned sufAbove = (unsigned)__shfl((int)p, L + 1, 64);
    if (L == 63) sufAbove = 0u;

    if (lane == L) {
        unsigned cum = sufAbove;
        int fb = L * 64;
        bool found = false;
        #pragma unroll
        for (int q = 15; q >= 0; --q) {          // descending bins: w,z,y,x
            cum += c[q].w; if (!found && cum >= K) { fb = L * 64 + q * 4 + 3; found = true; }
            cum += c[q].z; if (!found && cum >= K) { fb = L * 64 + q * 4 + 2; found = true; }
            cum += c[q].y; if (!found && cum >= K) { fb = L * 64 + q * 4 + 1; found = true; }
            cum += c[q].x; if (!found && cum >= K) { fb = L * 64 + q * 4 + 0; found = true; }
        }
        *s_dst = fb;
    }
}

// ONEPASS: score/decode (r9-verified, registers only) -> global hist atomics
// -> last-block FB (verified scan) -> all blocks spin on flag -> candidate
// append via coherent atomic payload stores -> last block runs verified
// LDS NMS with NaN-lock shortcut. All cross-block data moves via device-scope
// atomics; the two ACQ_REL RMWs per block have no dirty plain stores to
// publish. Co-residency: 682 blocks, >=9 blocks/CU capacity (LDS 16.4KB).
__global__ void __launch_bounds__(BT, 2)
fcos_onepass(const float* __restrict__ logits,
             const float* __restrict__ boxreg,
             const float* __restrict__ ctr,
             const float* __restrict__ anchors,
             unsigned* __restrict__ hist,
             unsigned* __restrict__ cnt,
             unsigned* __restrict__ doneA,
             unsigned* __restrict__ doneC,
             unsigned* __restrict__ flag,
             unsigned long long* __restrict__ payload,
             float* __restrict__ out) {
    // LDS union: phase A staging (11648 B) / FB hist copy (16384 B) /
    // NMS arrays (14336 B). Reuse separated by __syncthreads.
    __shared__ __align__(16) unsigned char lds_raw[16384];
    __shared__ float s_best[2];
    __shared__ int   s_bid[2];
    __shared__ int   s_fb, s_islast;
    __shared__ unsigned s_flagv;

    const int tid  = threadIdx.x;
    const int lane = tid & 63;
    const int w    = tid >> 6;
    const int bid  = blockIdx.x;
    const int wavebase = bid * BT + w * 64;

    // ================= Phase A: score + label + decode (registers) ==========
    float* pool = (float*)lds_raw;
    float* buf  = pool + w * 1456;
    float4* l4  = (float4*)buf;

    const int r  = lane & 15;            // local row within a chunk
    const int q  = lane >> 4;            // column quarter
    const int q0 = q * 23;
    const int qn = (q == 3) ? 22 : 23;   // [0,23)[23,46)[46,69)[69,91)

    float m = -INFINITY;
    int   lab = 0;

    #pragma unroll
    for (int c = 0; c < 4; ++c) {
        // stage 16 rows = 364 float4, coalesced; wave-private -> no barrier
        const float4* g4 = (const float4*)logits +
                           ((size_t)(wavebase + c * 16) * 91) / 4;
        #pragma unroll
        for (int k = 0; k < 6; ++k) {
            int idx = k * 64 + lane;
            if (idx < 364) l4[idx] = g4[idx];
        }
        const float* rp = buf + r * 91 + q0;
        float cm = rp[0];
        int   ci = q0;
        #pragma unroll
        for (int j = 1; j < 23; ++j) {
            if (j < qn) {
                float v = rp[j];
                if (v > cm) { cm = v; ci = q0 + j; }   // strict >: first max
            }
        }
        float om = __shfl_xor(cm, 16, 64);
        int   oi = __shfl_xor(ci, 16, 64);
        if (om > cm || (om == cm && oi < ci)) { cm = om; ci = oi; }
        om = __shfl_xor(cm, 32, 64);
        oi = __shfl_xor(ci, 32, 64);
        if (om > cm || (om == cm && oi < ci)) { cm = om; ci = oi; }
        if (c == q) { m = cm; lab = ci; }              // own row = own chunk
    }

    const int i = wavebase + lane;
    const float s = sqrtf(sigmoidf_(m) * sigmoidf_(ctr[i]));
    const int bin = min(max((int)(s * (float)NBINS), 0), NBINS - 1);

    float4 A = ((const float4*)anchors)[i];
    float4 R = ((const float4*)boxreg)[i];
    float cx = 0.5f * (A.x + A.z);
    float cy = 0.5f * (A.y + A.w);
    float ww = A.z - A.x;
    float hh = A.w - A.y;
    const float X1 = cx - R.x * ww;
    const float Y1 = cy - R.y * hh;
    const float X2 = cx + R.z * ww;
    const float Y2 = cy + R.w * hh;
    const float AR = fmaxf(X2 - X1, 0.0f) * fmaxf(Y2 - Y1, 0.0f);

    atomicAdd(&hist[bin], 1u);           // device-scope (m20)
    __syncthreads();                     // drains vmcnt: block's adds issued

    // ================= Phase B: last block computes FB ======================
    if (tid == 0) {
        unsigned old = __hip_atomic_fetch_add(doneA, 1u, __ATOMIC_ACQ_REL,
                                              __HIP_MEMORY_SCOPE_AGENT);
        s_islast = (old == NB - 1) ? 1 : 0;
    }
    __syncthreads();
    if (s_islast) {
        // hist lines: only coherence-point atomics touched them this dispatch;
        // the ACQ_REL acquire above invalidated local caches -> plain loads OK.
        unsigned* lhist = (unsigned*)lds_raw;
        const uint4* gh4 = (const uint4*)hist;   // 1024 uint4
        uint4* lh4 = (uint4*)lhist;
        #pragma unroll
        for (int k = 0; k < 8; ++k) lh4[k * BT + tid] = gh4[k * BT + tid];
        __syncthreads();
        if (tid < 64) scan_thresh(lhist, lane, K_CAND, &s_fb);
        __syncthreads();
        if (tid == 0)
            __hip_atomic_store(flag, (unsigned)s_fb | 0x10000u,
                               __ATOMIC_RELAXED, __HIP_MEMORY_SCOPE_AGENT);
    }

    // ================= spin: FB broadcast via the flag ======================
    if (tid == 0) {
        unsigned f;
        while ((f = __hip_atomic_load(flag, __ATOMIC_RELAXED,
                                      __HIP_MEMORY_SCOPE_AGENT)) == 0u)
            __builtin_amdgcn_s_sleep(2);
        s_flagv = f;
    }
    __syncthreads();
    const unsigned FB = s_flagv & 0xFFFFu;

    // ================= Phase C: append candidates (coherent payload) =======
    if ((unsigned)bin >= FB) {
        unsigned pos = atomicAdd(cnt, 1u);
        if (pos < CAP) {
            unsigned long long* p = payload + (size_t)pos * 4;
            __hip_atomic_store(p + 0, pack2f(s, AR),  __ATOMIC_RELAXED, __HIP_MEMORY_SCOPE_AGENT);
            __hip_atomic_store(p + 1, pack2f(X1, Y1), __ATOMIC_RELAXED, __HIP_MEMORY_SCOPE_AGENT);
            __hip_atomic_store(p + 2, pack2f(X2, Y2), __ATOMIC_RELAXED, __HIP_MEMORY_SCOPE_AGENT);
            __hip_atomic_store(p + 3, (unsigned long long)lab,
                               __ATOMIC_RELAXED, __HIP_MEMORY_SCOPE_AGENT);
        }
    }
    __syncthreads();                     // drains block's atomics
    if (tid == 0) {
        unsigned old = __hip_atomic_fetch_add(doneC, 1u, __ATOMIC_ACQ_REL,
                                              __HIP_MEMORY_SCOPE_AGENT);
        s_islast = (old == NB - 1) ? 1 : 0;
    }
    __syncthreads();
    if (!s_islast) return;

    // ================= Phase D: last block runs NMS =========================
    const int M = (int)min(__hip_atomic_load(cnt, __ATOMIC_RELAXED,
                                             __HIP_MEMORY_SCOPE_AGENT),
                           (unsigned)CAP);
    float* ls   = (float*)lds_raw;
    float* lx1  = (float*)lds_raw + 512;
    float* ly1  = (float*)lds_raw + 1024;
    float* lx2  = (float*)lds_raw + 1536;
    float* ly2  = (float*)lds_raw + 2048;
    float* lar  = (float*)lds_raw + 2560;
    int*   llab = (int*)lds_raw + 3072;

    for (int c = tid; c < CAP; c += BT) {
        if (c < M) {
            const unsigned long long* p = payload + (size_t)c * 4;
            unsigned long long u0 = __hip_atomic_load(p + 0, __ATOMIC_RELAXED, __HIP_MEMORY_SCOPE_AGENT);
            unsigned long long u1 = __hip_atomic_load(p + 1, __ATOMIC_RELAXED, __HIP_MEMORY_SCOPE_AGENT);
            unsigned long long u2 = __hip_atomic_load(p + 2, __ATOMIC_RELAXED, __HIP_MEMORY_SCOPE_AGENT);
            unsigned long long u3 = __hip_atomic_load(p + 3, __ATOMIC_RELAXED, __HIP_MEMORY_SCOPE_AGENT);
            float sc, ar, x1, y1, x2, y2;
            unpack2f(u0, sc, ar);
            unpack2f(u1, x1, y1);
            unpack2f(u2, x2, y2);
            ls[c] = sc; lar[c] = ar;
            lx1[c] = x1; ly1[c] = y1; lx2[c] = x2; ly2[c] = y2;
            llab[c] = (int)u3;
        } else {
            ls[c] = -INFINITY;
            lx1[c] = ly1[c] = lx2[c] = ly2[c] = 0.0f;
            lar[c] = 0.0f;
            llab[c] = 0;
        }
    }
    __syncthreads();

    // greedy NMS (verified r5/r6 2-wave version), NaN-lock shortcut
    for (int it = 0; it < MAX_OUT; ++it) {
        float b = -INFINITY;
        int id = 0;
        for (int base = 0; base < CAP; base += BT) {
            int c = base + tid;
            float v = ls[c];
            if (v > b) { b = v; id = c; }
        }
        #pragma unroll
        for (int d = 32; d >= 1; d >>= 1) {
            float ob = __shfl_xor(b, d, 64);
            int   oid = __shfl_xor(id, d, 64);
            if (ob > b) { b = ob; id = oid; }
        }
        if (lane == 0) { s_best[w] = b; s_bid[w] = id; }
        __syncthreads();
        float gb = s_best[0];
        int gid = s_bid[0];
        if (s_best[1] > gb) { gb = s_best[1]; gid = s_bid[1]; }

        float sx1 = lx1[gid], sy1 = ly1[gid], sx2 = lx2[gid], sy2 = ly2[gid];
        float sar = lar[gid];
        int   slab = llab[gid];

        if (tid == 0) {
            out[it * 4 + 0] = sx1;
            out[it * 4 + 1] = sy1;
            out[it * 4 + 2] = sx2;
            out[it * 4 + 3] = sy2;
            out[4 * MAX_OUT + it] = (float)slab;
            out[5 * MAX_OUT + it] = gb;
        }

        // Lock: zero-area winner -> inter==0 with every box, self-iou=0/0=NaN,
        // NaN>0.6 false -> nothing suppressed -> reference re-selects this
        // same box for every remaining slot.
        if (sar == 0.0f) {
            for (int rr = it + 1 + tid; rr < MAX_OUT; rr += BT) {
                out[rr * 4 + 0] = sx1;
                out[rr * 4 + 1] = sy1;
                out[rr * 4 + 2] = sx2;
                out[rr * 4 + 3] = sy2;
                out[4 * MAX_OUT + rr] = (float)slab;
                out[5 * MAX_OUT + rr] = gb;
            }
            return;
        }

        for (int base = 0; base < CAP; base += BT) {
            int c = base + tid;
            float ix1 = fmaxf(sx1, lx1[c]);
            float iy1 = fmaxf(sy1, ly1[c]);
            float ix2 = fminf(sx2, lx2[c]);
            float iy2 = fminf(sy2, ly2[c]);
            float inter = fmaxf(ix2 - ix1, 0.0f) * fmaxf(iy2 - iy1, 0.0f);
            float iou = inter / (sar + lar[c] - inter);
            if (iou > IOU_TH) ls[c] = -INFINITY;
        }
        __syncthreads();
    }
}

extern "C" void kernel_launch(void* const* d_in, const int* in_sizes, int n_in,
                              void* d_out, int out_size, void* d_ws, size_t ws_size,
                              hipStream_t stream) {
    const float* logits  = (const float*)d_in[0];
    const float* boxreg  = (const float*)d_in[1];
    const float* ctr     = (const float*)d_in[2];
    const float* anchors = (const float*)d_in[3];
    float* out = (float*)d_out;

    char* ws = (char*)d_ws;
    unsigned* hist  = (unsigned*)(ws + 0);
    unsigned* cnt   = (unsigned*)(ws + 16384);
    unsigned* doneA = (unsigned*)(ws + 16388);
    unsigned* doneC = (unsigned*)(ws + 16392);
    unsigned* flag  = (unsigned*)(ws + 16396);
    unsigned long long* payload = (unsigned long long*)(ws + 16400);

    hipMemsetAsync(ws, 0, WS_HDR, stream);   // re-zeroed on every graph replay
    fcos_onepass<<<NB, BT, 0, stream>>>(logits, boxreg, ctr, anchors,
                                        hist, cnt, doneA, doneC, flag,
                                        payload, out);
}

// Round 12
// 30.927 us; speedup vs baseline: 2.9996x; 2.9996x over previous
//
#include <hip/hip_runtime.h>
#include <math.h>

#define N_ANCH 87296
#define NCLS 91
#define NBINS 4096
#define K_CAND 256
#define CAP 512
#define MAX_OUT 100
#define IOU_TH 0.6f
#define NB1 682
#define BT1 128
#define T2 1024          // K2 threads (16 waves)
#define NB16 10912       // N_ANCH*2B / 16B = uint4 count of bin array

// CHAMPION (r9 structure, best measured 30.39 µs).
// ws layout (bytes):
//        0: bins  (N_ANCH*2 = 174592)  u16 bin index per anchor
//   174592: pbox  (N_ANCH*16 = 1396736)  ends 1571328   (16B aligned)
//  1571328: pmeta (N_ANCH*16 = 1396736)  {area, label, score, 0}
// no memset required: every cell consumed is written by K1 first.

__device__ __forceinline__ float sigmoidf_(float x) {
    return 1.0f / (1.0f + expf(-x));
}

// K1: per-anchor score + label + box decode. Wave-private LDS staging in
// 4 chunks of 16 rows (5.8 KB/wave, NO barriers): stage 364 float4 coalesced,
// lane l reduces local row (l&15), col-quarter (l>>4) tracking (max,idx),
// shfl_xor(16)+shfl_xor(32) combine -> every lane has full row result; lane
// keeps chunk (l>>4). 11.6 KB LDS/block + launch_bounds(128,4) -> 16 waves/CU.
__global__ void __launch_bounds__(BT1, 4)
score_decode_kernel(const float* __restrict__ logits,
                    const float* __restrict__ boxreg,
                    const float* __restrict__ ctr,
                    const float* __restrict__ anchors,
                    unsigned short* __restrict__ bins,
                    float4* __restrict__ pbox,
                    float4* __restrict__ pmeta) {
    __shared__ float pool[2 * 16 * 91];   // 2 waves x 1456 floats = 11648 B
    const int tid  = threadIdx.x;
    const int lane = tid & 63;
    const int w    = tid >> 6;
    const int bid  = blockIdx.x;
    const int wavebase = bid * BT1 + w * 64;

    float*  buf = pool + w * 1456;
    float4* l4  = (float4*)buf;

    const int r  = lane & 15;            // local row within a chunk
    const int q  = lane >> 4;            // column quarter
    const int q0 = q * 23;
    const int qn = (q == 3) ? 22 : 23;   // quarters: [0,23)[23,46)[46,69)[69,91)

    float m = -INFINITY;                 // own anchor's max logit
    int   lab = 0;                       // own anchor's argmax (first-max)

    #pragma unroll
    for (int c = 0; c < 4; ++c) {
        // stage 16 rows = 1456 floats = 364 float4 (coalesced, 16B-aligned)
        const float4* g4 = (const float4*)logits +
                           ((size_t)(wavebase + c * 16) * 91) / 4;
        #pragma unroll
        for (int k = 0; k < 6; ++k) {
            int idx = k * 64 + lane;
            if (idx < 364) l4[idx] = g4[idx];
        }
        // same-wave DS ordering + lgkmcnt: no barrier needed (wave-private buf)
        const float* rp = buf + r * 91 + q0;
        float cm = rp[0];
        int   ci = q0;
        #pragma unroll
        for (int j = 1; j < 23; ++j) {
            if (j < qn) {
                float v = rp[j];
                if (v > cm) { cm = v; ci = q0 + j; }   // strict >: first max
            }
        }
        // combine 4 quarters; on tie keep lower index (jnp.argmax first-max)
        float om = __shfl_xor(cm, 16, 64);
        int   oi = __shfl_xor(ci, 16, 64);
        if (om > cm || (om == cm && oi < ci)) { cm = om; ci = oi; }
        om = __shfl_xor(cm, 32, 64);
        oi = __shfl_xor(ci, 32, 64);
        if (om > cm || (om == cm && oi < ci)) { cm = om; ci = oi; }

        if (c == (lane >> 4)) { m = cm; lab = ci; }   // own row = own chunk
    }

    const int i = wavebase + lane;
    const float s = sqrtf(sigmoidf_(m) * sigmoidf_(ctr[i]));
    const int bin = min(max((int)(s * (float)NBINS), 0), NBINS - 1);
    bins[i] = (unsigned short)bin;

    float4 A = ((const float4*)anchors)[i];
    float4 R = ((const float4*)boxreg)[i];
    float cx = 0.5f * (A.x + A.z);
    float cy = 0.5f * (A.y + A.w);
    float ww = A.z - A.x;
    float hh = A.w - A.y;
    float4 bb;
    bb.x = cx - R.x * ww;
    bb.y = cy - R.y * hh;
    bb.z = cx + R.z * ww;
    bb.w = cy + R.w * hh;
    pbox[i] = bb;
    float4 mt;
    mt.x = fmaxf(bb.z - bb.x, 0.0f) * fmaxf(bb.w - bb.y, 0.0f);
    mt.y = (float)lab;
    mt.z = s;
    mt.w = 0.0f;
    pmeta[i] = mt;
}

// K2: single WG (verified r8 kernel). Bins loaded ONCE into registers ->
// LDS hist -> wave0 suffix-scan threshold -> compact from registers ->
// 32B gather per candidate -> register NMS with NaN-lock shortcut.
__global__ void __launch_bounds__(T2)
select_nms_kernel(const unsigned short* __restrict__ bins,
                  const float4* __restrict__ pbox,
                  const float4* __restrict__ pmeta,
                  float* __restrict__ out) {
    __shared__ unsigned hist[NBINS];     // 16 KB
    __shared__ int      lidx[CAP];
    __shared__ unsigned cnt;
    __shared__ int      s_fb;
    __shared__ float    s_best[16];
    __shared__ int      s_bid[16];
    __shared__ float    s_box[5];
    __shared__ int      s_lab;

    const int tid  = threadIdx.x;
    const int lane = tid & 63;
    const int wid  = tid >> 6;

    for (int b = tid; b < NBINS; b += T2) hist[b] = 0u;
    if (tid == 0) cnt = 0u;
    __syncthreads();

    // ---- single global read: bins -> registers ----
    const uint4* b4 = (const uint4*)bins;   // NB16 uint4
    uint4 bv[11];
    #pragma unroll
    for (int k = 0; k < 11; ++k) {
        int idx = k * T2 + tid;
        if (idx < NB16) {
            bv[k] = b4[idx];
        } else {
            uint4 z; z.x = z.y = z.z = z.w = 0u;   // bin 0 sentinel: inert
            bv[k] = z;
        }
    }

    // ---- hist from registers (LDS atomics) ----
    #pragma unroll
    for (int k = 0; k < 11; ++k) {
        unsigned vv[4] = {bv[k].x, bv[k].y, bv[k].z, bv[k].w};
        #pragma unroll
        for (int j = 0; j < 4; ++j) {
            atomicAdd(&hist[vv[j] & 0xFFFFu], 1u);
            atomicAdd(&hist[vv[j] >> 16], 1u);
        }
    }
    __syncthreads();

    // ---- threshold find (wave 0; verified suffix-scan) ----
    if (tid < 64) {
        const uint4* h4 = (const uint4*)hist;   // 1024 uint4
        uint4 c[16];
        #pragma unroll
        for (int q = 0; q < 16; ++q) c[q] = h4[lane * 16 + q];

        unsigned local = 0;
        #pragma unroll
        for (int q = 0; q < 16; ++q) local += c[q].x + c[q].y + c[q].z + c[q].w;

        unsigned p = local;                      // suffix-inclusive scan
        #pragma unroll
        for (int d = 1; d < 64; d <<= 1) {
            unsigned t = (unsigned)__shfl_down((int)p, d, 64);
            if (lane + d < 64) p += t;
        }
        unsigned long long mask = __ballot(p >= K_CAND);
        int L = 63 - __clzll(mask);
        unsigned sufAbove = (unsigned)__shfl((int)p, L + 1, 64);
        if (L == 63) sufAbove = 0u;

        if (lane == L) {
            unsigned cum = sufAbove;
            int fb = L * 64;
            bool found = false;
            #pragma unroll
            for (int q = 15; q >= 0; --q) {      // descending bins: w,z,y,x
                cum += c[q].w; if (!found && cum >= K_CAND) { fb = L * 64 + q * 4 + 3; found = true; }
                cum += c[q].z; if (!found && cum >= K_CAND) { fb = L * 64 + q * 4 + 2; found = true; }
                cum += c[q].y; if (!found && cum >= K_CAND) { fb = L * 64 + q * 4 + 1; found = true; }
                cum += c[q].x; if (!found && cum >= K_CAND) { fb = L * 64 + q * 4 + 0; found = true; }
            }
            s_fb = fb;
        }
    }
    __syncthreads();
    const unsigned FB = (unsigned)s_fb;

    // ---- compact from registers ----
    #pragma unroll
    for (int k = 0; k < 11; ++k) {
        int idx = k * T2 + tid;
        if (idx < NB16) {
            unsigned vv[4] = {bv[k].x, bv[k].y, bv[k].z, bv[k].w};
            #pragma unroll
            for (int j = 0; j < 4; ++j) {
                unsigned lo = vv[j] & 0xFFFFu;
                unsigned hi = vv[j] >> 16;
                if (lo >= FB) {
                    unsigned pos = atomicAdd(&cnt, 1u);
                    if (pos < CAP) lidx[pos] = idx * 8 + 2 * j;
                }
                if (hi >= FB) {
                    unsigned pos = atomicAdd(&cnt, 1u);
                    if (pos < CAP) lidx[pos] = idx * 8 + 2 * j + 1;
                }
            }
        }
    }
    __syncthreads();
    const int M = (int)min(cnt, (unsigned)CAP);

    // ---- gather precomputed decode: thread t < M owns candidate t ----
    float SC, X1, Y1, X2, Y2, AR;
    int LAB;
    if (tid < M) {
        int ai = lidx[tid];
        float4 bb = pbox[ai];
        float4 mt = pmeta[ai];
        X1 = bb.x; Y1 = bb.y; X2 = bb.z; Y2 = bb.w;
        AR = mt.x;
        LAB = (int)mt.y;
        SC = mt.z;
    } else {
        SC = -INFINITY;
        X1 = Y1 = X2 = Y2 = AR = 0.0f;
        LAB = 0;
    }
    __syncthreads();

    // ---- greedy NMS (verified register version, 16-wave argmax) ----
    for (int it = 0; it < MAX_OUT; ++it) {
        float b = SC;
        int id = tid;
        #pragma unroll
        for (int d = 32; d >= 1; d >>= 1) {
            float ob = __shfl_xor(b, d, 64);
            int   oid = __shfl_xor(id, d, 64);
            if (ob > b) { b = ob; id = oid; }
        }
        if (lane == 0) { s_best[wid] = b; s_bid[wid] = id; }
        __syncthreads();
        float gb = s_best[0];
        int gid = s_bid[0];
        #pragma unroll
        for (int w = 1; w < 16; ++w) {
            if (s_best[w] > gb) { gb = s_best[w]; gid = s_bid[w]; }
        }
        if (tid == gid) {
            s_box[0] = X1; s_box[1] = Y1; s_box[2] = X2; s_box[3] = Y2;
            s_box[4] = AR; s_lab = LAB;
        }
        __syncthreads();
        float sx1 = s_box[0], sy1 = s_box[1], sx2 = s_box[2], sy2 = s_box[3];
        float sar = s_box[4];
        int   slab = s_lab;

        if (tid == 0) {
            out[it * 4 + 0] = sx1;
            out[it * 4 + 1] = sy1;
            out[it * 4 + 2] = sx2;
            out[it * 4 + 3] = sy2;
            out[4 * MAX_OUT + it] = (float)slab;
            out[5 * MAX_OUT + it] = gb;
        }

        // Lock: zero-area winner -> inter==0 with every box, self-iou=0/0=NaN,
        // NaN>0.6 false -> nothing suppressed -> reference re-selects this
        // same box for every remaining slot.
        if (sar == 0.0f) {
            for (int r = it + 1 + tid; r < MAX_OUT; r += T2) {
                out[r * 4 + 0] = sx1;
                out[r * 4 + 1] = sy1;
                out[r * 4 + 2] = sx2;
                out[r * 4 + 3] = sy2;
                out[4 * MAX_OUT + r] = (float)slab;
                out[5 * MAX_OUT + r] = gb;
            }
            return;
        }

        float ix1 = fmaxf(sx1, X1);
        float iy1 = fmaxf(sy1, Y1);
        float ix2 = fminf(sx2, X2);
        float iy2 = fminf(sy2, Y2);
        float inter = fmaxf(ix2 - ix1, 0.0f) * fmaxf(iy2 - iy1, 0.0f);
        float iou = inter / (sar + AR - inter);
        if (iou > IOU_TH) SC = -INFINITY;
        __syncthreads();
    }
}

extern "C" void kernel_launch(void* const* d_in, const int* in_sizes, int n_in,
                              void* d_out, int out_size, void* d_ws, size_t ws_size,
                              hipStream_t stream) {
    const float* logits  = (const float*)d_in[0];
    const float* boxreg  = (const float*)d_in[1];
    const float* ctr     = (const float*)d_in[2];
    const float* anchors = (const float*)d_in[3];
    float* out = (float*)d_out;

    char* ws = (char*)d_ws;
    unsigned short* bins = (unsigned short*)(ws + 0);
    float4*         pbox = (float4*)(ws + 174592);
    float4*         pmeta= (float4*)(ws + 1571328);

    score_decode_kernel<<<NB1, BT1, 0, stream>>>(logits, boxreg, ctr, anchors,
                                                 bins, pbox, pmeta);
    select_nms_kernel<<<1, T2, 0, stream>>>(bins, pbox, pmeta, out);
}